// Round 27
// baseline (6215.288 us; speedup 1.0000x reference)
//
#include <hip/hip_runtime.h>
#include <math.h>

#define N_PTS 262144
#define KC 256
#define DIM 64
#define MAX_ITERS 10
#define CHUNK 256

// ===========================================================================
// Bit-exact XLA:CPU f32 arithmetic (validated R11-R26 — DO NOT ALTER):
//   x2/c2: rounded squares (fmaf(v,v,0)) + strict sequential f32 add chain
//   dot:   ascending-k FMA chain;  d2 = (x2 + c2) - 2*dot
//   argmin: strict-< first-min, first-NaN override
//   segment_sum: per (k,d), i-ascending sequential plain f32 adds
//   update: f32 sums/counts division (0/0 -> NaN)
// R27: assign_k — force SMEM (s_load) path for centroid reads. R26 analysis:
// 75us of excess VALU issue == per-lane vector loads + addr arithmetic for
// the (uniform!) C reads; divergent-looking early-outs defeat uniformity
// analysis. readfirstlane-rebuilt base pointer is uniform BY CONSTRUCTION ->
// s_load selection, SMEM pipe, zero VALU addr work. Arithmetic unchanged.
// ===========================================================================

__device__ __forceinline__ float seq_rowsum_sq64(const float* p)
{
    float s = fmaf(p[0], p[0], 0.f);
    #pragma unroll
    for (int d = 1; d < DIM; ++d) s = s + fmaf(p[d], p[d], 0.f);
    return s;
}

// rebuild a wave-uniform pointer through readfirstlane (identity on uniform
// input, but provably uniform to the compiler -> scalar-load selection)
__device__ __forceinline__ const float* uniform_ptr(const float* p)
{
    unsigned long long a = (unsigned long long)(uintptr_t)p;
    unsigned lo = __builtin_amdgcn_readfirstlane((unsigned)a);
    unsigned hi = __builtin_amdgcn_readfirstlane((unsigned)(a >> 32));
    return (const float*)(uintptr_t)(((unsigned long long)hi << 32) | lo);
}

__global__ void detect_idx(const int* __restrict__ a, int* __restrict__ mode)
{
    int zeros = 0;
    for (int j = 1; j < 256; j += 2) zeros += (a[j] == 0);
    *mode = (zeros >= 2) ? 1 : 0;
}

__global__ __launch_bounds__(256) void init_gather(
    const float* __restrict__ data, const void* __restrict__ idxraw,
    const int* __restrict__ mode,
    float* __restrict__ C, int* __restrict__ done)
{
    int t = blockIdx.x * 256 + threadIdx.x;
    if (t < KC * DIM) {
        int k = t >> 6;
        long long src = (*mode) ? ((const long long*)idxraw)[k]
                                : (long long)((const int*)idxraw)[k];
        C[t] = data[(size_t)src * DIM + (t & 63)];
    }
    if (t == 0) *done = 0;
}

__global__ __launch_bounds__(256) void c2_init(
    const float* __restrict__ C, float* __restrict__ c2, int* __restrict__ nanidx)
{
    int k = threadIdx.x;
    float p[DIM];
    #pragma unroll
    for (int d = 0; d < DIM; ++d) p[d] = C[k * DIM + d];
    c2[k] = seq_rowsum_sq64(p);
    __syncthreads();
    if (k == 0) {
        int ni = -1;
        for (int kk = 0; kk < KC; ++kk)
            if (isnan(c2[kk])) { ni = kk; break; }
        *nanidx = ni;
    }
}

// assign: validated arithmetic; centroid reads via uniform (SGPR) pointer.
__global__ __launch_bounds__(256, 1) void assign_k(
    const float* __restrict__ data, const float* __restrict__ Cin,
    const float* __restrict__ c2in, const int* __restrict__ nanidx,
    int* __restrict__ labels, const int* __restrict__ done)
{
    if (*done) return;
    int i = blockIdx.x * 256 + threadIdx.x;
    int ni = *nanidx;
    if (ni >= 0) { labels[i] = ni; return; }

    const float* C  = uniform_ptr(Cin);
    const float* c2 = uniform_ptr(c2in);

    float p[DIM];
    const float4* r = (const float4*)(data + (size_t)i * DIM);
    #pragma unroll
    for (int j = 0; j < 16; ++j) {
        float4 v = r[j];
        p[4 * j + 0] = v.x; p[4 * j + 1] = v.y;
        p[4 * j + 2] = v.z; p[4 * j + 3] = v.w;
    }
    float xx = seq_rowsum_sq64(p);

    float bestd = INFINITY;
    int best = 0;
    for (int k0 = 0; k0 < KC; k0 += 8) {
        const float* c0 = C + (size_t)k0 * DIM;
        float a0 = 0.f, a1 = 0.f, a2 = 0.f, a3 = 0.f;
        float a4 = 0.f, a5 = 0.f, a6 = 0.f, a7 = 0.f;
        #pragma unroll
        for (int d = 0; d < DIM; ++d) {
            float pd = p[d];
            a0 = fmaf(c0[d],           pd, a0);
            a1 = fmaf(c0[DIM + d],     pd, a1);
            a2 = fmaf(c0[2 * DIM + d], pd, a2);
            a3 = fmaf(c0[3 * DIM + d], pd, a3);
            a4 = fmaf(c0[4 * DIM + d], pd, a4);
            a5 = fmaf(c0[5 * DIM + d], pd, a5);
            a6 = fmaf(c0[6 * DIM + d], pd, a6);
            a7 = fmaf(c0[7 * DIM + d], pd, a7);
        }
        float d0 = (xx + c2[k0 + 0]) - 2.f * a0;
        float d1 = (xx + c2[k0 + 1]) - 2.f * a1;
        float d2v = (xx + c2[k0 + 2]) - 2.f * a2;
        float d3 = (xx + c2[k0 + 3]) - 2.f * a3;
        float d4 = (xx + c2[k0 + 4]) - 2.f * a4;
        float d5 = (xx + c2[k0 + 5]) - 2.f * a5;
        float d6 = (xx + c2[k0 + 6]) - 2.f * a6;
        float d7 = (xx + c2[k0 + 7]) - 2.f * a7;
        if (d0 < bestd) { bestd = d0; best = k0 + 0; }
        if (d1 < bestd) { bestd = d1; best = k0 + 1; }
        if (d2v < bestd) { bestd = d2v; best = k0 + 2; }
        if (d3 < bestd) { bestd = d3; best = k0 + 3; }
        if (d4 < bestd) { bestd = d4; best = k0 + 4; }
        if (d5 < bestd) { bestd = d5; best = k0 + 5; }
        if (d6 < bestd) { bestd = d6; best = k0 + 6; }
        if (d7 < bestd) { bestd = d7; best = k0 + 7; }
    }
    labels[i] = best;
}

// ---- sort pass A: per-chunk histogram
__global__ __launch_bounds__(256) void hist_k(
    const int* __restrict__ labels, int* __restrict__ hist,
    const int* __restrict__ done)
{
    if (*done) return;
    __shared__ int h[KC];
    int b = blockIdx.x;
    h[threadIdx.x] = 0;
    __syncthreads();
    int base = b * 1024;
    for (int j = threadIdx.x; j < 1024; j += 256)
        atomicAdd(&h[labels[base + j]], 1);
    __syncthreads();
    hist[b * KC + threadIdx.x] = h[threadIdx.x];
}

// ---- sort pass B: column prefix + exclusive scan (integer, order-free)
__global__ __launch_bounds__(256) void prefix_k(
    int* __restrict__ hist, int* __restrict__ seg_start,
    float* __restrict__ counts, const int* __restrict__ done)
{
    if (*done) return;
    int k = threadIdx.x;
    int run = 0;
    #pragma unroll 8
    for (int b = 0; b < 256; ++b) {
        int v = hist[b * KC + k];
        hist[b * KC + k] = run;
        run += v;
    }
    __shared__ int sc[KC];
    sc[k] = run;
    __syncthreads();
    for (int off = 1; off < KC; off <<= 1) {
        int v = (k >= off) ? sc[k - off] : 0;
        __syncthreads();
        sc[k] += v;
        __syncthreads();
    }
    int base = sc[k] - run;
    seg_start[k] = base;
    if (k == 0) seg_start[KC] = N_PTS;
    counts[k] = (float)run;
    #pragma unroll 8
    for (int b = 0; b < 256; ++b)
        hist[b * KC + k] += base;
}

// ---- sort pass C: order-preserving scatter (ascending j per chunk)
__global__ __launch_bounds__(256) void scatter_k(
    const int* __restrict__ labels, const int* __restrict__ hist,
    int* __restrict__ order, const int* __restrict__ done)
{
    if (*done) return;
    __shared__ int lab_s[1024];
    int b = blockIdx.x, k = threadIdx.x;
    int base = b * 1024;
    for (int j = k; j < 1024; j += 256) lab_s[j] = labels[base + j];
    __syncthreads();
    int pos = hist[b * KC + k];
    for (int j = 0; j < 1024; ++j) {
        if (lab_s[j] == k) order[pos++] = base + j;
    }
}

// ---- segment sum, transposed+swizzled LDS pipeline (R24 validated).
__global__ __launch_bounds__(512, 1) void sum_pipe4(
    const float* __restrict__ data, const int* __restrict__ order,
    const int* __restrict__ seg_start, float* __restrict__ sums,
    const int* __restrict__ done)
{
    if (*done) return;
    __shared__ float buf[2][DIM][CHUNK];    // 128 KB
    int k = blockIdx.x;
    int t = threadIdx.x;
    int beg = seg_start[k], end = seg_start[k + 1];
    int n = end - beg;
    int nchunk = (n + CHUNK - 1) / CHUNK;
    bool stager = (t >= 64);
    int st = t - 64;                        // 0..447

    int gg[3], qq[3];
    #pragma unroll
    for (int i = 0; i < 3; ++i) {
        int G = st + i * 448;
        gg[i] = G >> 4;
        qq[i] = G & 15;
    }
    int ordA[12];
    const float4* d4 = (const float4*)data;

#define ORDX(cc)                                                              \
    {                                                                         \
        int _b = beg + (cc) * CHUNK;                                          \
        int _m = n - (cc) * CHUNK; if (_m > CHUNK) _m = CHUNK;                \
        _Pragma("unroll")                                                     \
        for (int i = 0; i < 3; ++i) {                                         \
            _Pragma("unroll")                                                 \
            for (int r = 0; r < 4; ++r) {                                     \
                int _rr = 4 * gg[i] + r; if (_rr >= _m) _rr = _m - 1;         \
                ordA[i * 4 + r] = order[_b + _rr];                            \
            }                                                                 \
        }                                                                     \
    }
#define STAGEX(cc, which)                                                     \
    {                                                                         \
        int _m = n - (cc) * CHUNK; if (_m > CHUNK) _m = CHUNK;                \
        int _ng = (_m + 3) >> 2;                                              \
        float4* _bp = (float4*)&buf[which][0][0];                             \
        _Pragma("unroll")                                                     \
        for (int i = 0; i < 3; ++i) {                                         \
            if (gg[i] < _ng) {                                                \
                float4 a0 = d4[(size_t)ordA[i * 4 + 0] * 16 + qq[i]];         \
                float4 a1 = d4[(size_t)ordA[i * 4 + 1] * 16 + qq[i]];         \
                float4 a2 = d4[(size_t)ordA[i * 4 + 2] * 16 + qq[i]];         \
                float4 a3 = d4[(size_t)ordA[i * 4 + 3] * 16 + qq[i]];         \
                int _d0 = qq[i] * 4;                                          \
                _bp[(_d0 + 0) * (CHUNK / 4) + (gg[i] ^ ((_d0 + 0) & 7))] =    \
                    make_float4(a0.x, a1.x, a2.x, a3.x);                      \
                _bp[(_d0 + 1) * (CHUNK / 4) + (gg[i] ^ ((_d0 + 1) & 7))] =    \
                    make_float4(a0.y, a1.y, a2.y, a3.y);                      \
                _bp[(_d0 + 2) * (CHUNK / 4) + (gg[i] ^ ((_d0 + 2) & 7))] =    \
                    make_float4(a0.z, a1.z, a2.z, a3.z);                      \
                _bp[(_d0 + 3) * (CHUNK / 4) + (gg[i] ^ ((_d0 + 3) & 7))] =    \
                    make_float4(a0.w, a1.w, a2.w, a3.w);                      \
            }                                                                 \
        }                                                                     \
    }

    if (stager && nchunk > 0) {
        ORDX(0);
        STAGEX(0, 0);
        if (nchunk > 1) ORDX(1);
    }
    __syncthreads();

    float s = 0.f;
    int x7 = t & 7;
    for (int c = 0; c < nchunk; ++c) {
        if (stager) {
            if (c + 1 < nchunk) STAGEX(c + 1, (c + 1) & 1);
            if (c + 2 < nchunk) ORDX(c + 2);
        } else {
            int m = n - c * CHUNK; if (m > CHUNK) m = CHUNK;
            int mg = m >> 2;
            int cur = c & 1;
            const float4* rp = (const float4*)&buf[cur][t][0];
            #pragma unroll 8
            for (int g = 0; g < mg; ++g) {
                float4 v = rp[g ^ x7];
                s = s + v.x; s = s + v.y; s = s + v.z; s = s + v.w;
            }
            for (int j = mg * 4; j < m; ++j)
                s = s + buf[cur][t][(((j >> 2) ^ x7) << 2) + (j & 3)];
        }
        __syncthreads();
    }
#undef ORDX
#undef STAGEX
    if (t < 64) sums[k * DIM + t] = s;
}

// fallback segment-sum (validated R11) when ws has no room for sort buffers
__global__ __launch_bounds__(64) void accum_scan(
    const float* __restrict__ data, const int* __restrict__ labels,
    float* __restrict__ sums, float* __restrict__ counts,
    const int* __restrict__ done)
{
    if (*done) return;
    int k = blockIdx.x;
    int d = threadIdx.x;
    __shared__ int lab_s[1024];
    float s = 0.f;
    int cnt = 0;
    for (int base = 0; base < N_PTS; base += 1024) {
        for (int j = d; j < 1024; j += 64) lab_s[j] = labels[base + j];
        __syncthreads();
        #pragma unroll 8
        for (int j = 0; j < 1024; ++j) {
            if (lab_s[j] == k) { s = s + data[(size_t)(base + j) * DIM + d]; ++cnt; }
        }
        __syncthreads();
    }
    sums[k * DIM + d] = s;
    if (d == 0) counts[k] = (float)cnt;
}

// ---- update + c2 fused (validated)
__global__ __launch_bounds__(256) void update_c2_k(
    float* __restrict__ C, const float* __restrict__ sums,
    const float* __restrict__ counts, float* __restrict__ c2,
    int* __restrict__ nanidx, int* __restrict__ done)
{
    if (*done) return;
    __shared__ double red[256];
    int k = threadIdx.x;

    float cnt = counts[k];
    float nc[DIM];
    double local = 0.0;
    #pragma unroll
    for (int d = 0; d < DIM; ++d) {
        float v = sums[k * DIM + d] / cnt;
        nc[d] = v;
        float old = C[k * DIM + d];
        double diff = (double)v - (double)old;
        local = fma(diff, diff, local);
        C[k * DIM + d] = v;
    }
    c2[k] = seq_rowsum_sq64(nc);

    red[k] = local;
    __syncthreads();
    if (k == 0) {
        int ni = -1;
        for (int kk = 0; kk < KC; ++kk)
            if (isnan(c2[kk])) { ni = kk; break; }
        *nanidx = ni;
    }
    for (int s = 128; s > 0; s >>= 1) {
        if (k < s) red[k] += red[k + s];
        __syncthreads();
    }
    if (k == 0 && red[0] < 1e-8) *done = 1;    // (1e-4)^2, NaN stays not-done
}

extern "C" void kernel_launch(void* const* d_in, const int* in_sizes, int n_in,
                              void* d_out, int out_size, void* d_ws, size_t ws_size,
                              hipStream_t stream)
{
    const float* data = (const float*)d_in[0];
    const void*  idx  = d_in[1];
    int* labels = (int*)d_out;

    float* C      = (float*)d_ws;               // 16384 f
    float* sums   = C + KC * DIM;               // 16384 f
    float* counts = sums + KC * DIM;            // 256 f
    float* c2     = counts + KC;                // 256 f
    int*   done      = (int*)(c2 + KC);
    int*   mode      = done + 1;
    int*   nanidx    = done + 2;
    int*   seg_start = done + 4;                // 257 ints
    int*   hist      = seg_start + 260;         // 65536 ints
    int*   order     = hist + KC * 256;         // 262144 ints
    size_t need_sort = (size_t)((char*)(order + N_PTS) - (char*)d_ws);
    bool fast = ws_size >= need_sort;           // ~1.4 MB

    detect_idx<<<1, 1, 0, stream>>>((const int*)idx, mode);
    init_gather<<<64, 256, 0, stream>>>(data, idx, mode, C, done);
    c2_init<<<1, 256, 0, stream>>>(C, c2, nanidx);

    for (int it = 0; it < MAX_ITERS; ++it) {
        assign_k<<<N_PTS / 256, 256, 0, stream>>>(data, C, c2, nanidx, labels, done);
        if (fast) {
            hist_k<<<256, 256, 0, stream>>>(labels, hist, done);
            prefix_k<<<1, 256, 0, stream>>>(hist, seg_start, counts, done);
            scatter_k<<<256, 256, 0, stream>>>(labels, hist, order, done);
            sum_pipe4<<<KC, 512, 0, stream>>>(data, order, seg_start, sums, done);
        } else {
            accum_scan<<<KC, 64, 0, stream>>>(data, labels, sums, counts, done);
        }
        update_c2_k<<<1, 256, 0, stream>>>(C, sums, counts, c2, nanidx, done);
    }
}

// Round 28
// 2686.524 us; speedup vs baseline: 2.3135x; 2.3135x over previous
//
#include <hip/hip_runtime.h>
#include <math.h>

#define N_PTS 262144
#define KC 256
#define DIM 64
#define MAX_ITERS 10
#define CHUNK 256

// ===========================================================================
// Bit-exact XLA:CPU f32 arithmetic (validated R11-R27 — DO NOT ALTER):
//   x2/c2: rounded squares (fmaf(v,v,0)) + strict sequential f32 add chain
//   dot:   ascending-k FMA chain;  d2 = (x2 + c2) - 2*dot
//   argmin: strict-< first-min, first-NaN override
//   segment_sum: per (k,d), i-ascending sequential plain f32 adds
//   update: f32 sums/counts division (0/0 -> NaN)
// R28: assign_k issue-ratio fix (R27's s_load path reverted — 504us, exposed
// lgkmcnt). (1) C staged in LDS: ds_read_b128 broadcast, no L1 thrash (C=64KB
// > 32KB L1). (2) M_TILE=2: each thread does points i and i+N/2, c amortized
// 2x. Load:FMA goes 1:1 -> 1:8. Chains still ascending-d per (pt,k);
// compares ascending-k. done/nanidx early-outs are block-uniform -> barrier
// legal.
// ===========================================================================

__device__ __forceinline__ float seq_rowsum_sq64(const float* p)
{
    float s = fmaf(p[0], p[0], 0.f);
    #pragma unroll
    for (int d = 1; d < DIM; ++d) s = s + fmaf(p[d], p[d], 0.f);
    return s;
}

__global__ void detect_idx(const int* __restrict__ a, int* __restrict__ mode)
{
    int zeros = 0;
    for (int j = 1; j < 256; j += 2) zeros += (a[j] == 0);
    *mode = (zeros >= 2) ? 1 : 0;
}

__global__ __launch_bounds__(256) void init_gather(
    const float* __restrict__ data, const void* __restrict__ idxraw,
    const int* __restrict__ mode,
    float* __restrict__ C, int* __restrict__ done)
{
    int t = blockIdx.x * 256 + threadIdx.x;
    if (t < KC * DIM) {
        int k = t >> 6;
        long long src = (*mode) ? ((const long long*)idxraw)[k]
                                : (long long)((const int*)idxraw)[k];
        C[t] = data[(size_t)src * DIM + (t & 63)];
    }
    if (t == 0) *done = 0;
}

__global__ __launch_bounds__(256) void c2_init(
    const float* __restrict__ C, float* __restrict__ c2, int* __restrict__ nanidx)
{
    int k = threadIdx.x;
    float p[DIM];
    #pragma unroll
    for (int d = 0; d < DIM; ++d) p[d] = C[k * DIM + d];
    c2[k] = seq_rowsum_sq64(p);
    __syncthreads();
    if (k == 0) {
        int ni = -1;
        for (int kk = 0; kk < KC; ++kk)
            if (isnan(c2[kk])) { ni = kk; break; }
        *nanidx = ni;
    }
}

// assign: validated arithmetic; LDS-staged C + 2-point register blocking.
// Thread handles points i0 = b*256+t and i1 = i0 + N/2. Grid = 512 blocks.
__global__ __launch_bounds__(256, 2) void assign_k(
    const float* __restrict__ data, const float* __restrict__ Cin,
    const float* __restrict__ c2, const int* __restrict__ nanidx,
    int* __restrict__ labels, const int* __restrict__ done)
{
    if (*done) return;                       // block-uniform
    __shared__ float Cs[KC * DIM];           // 64 KB
    int i0 = blockIdx.x * 256 + threadIdx.x;
    int i1 = i0 + N_PTS / 2;
    int ni = *nanidx;
    if (ni >= 0) { labels[i0] = ni; labels[i1] = ni; return; }   // uniform

    {   // cooperative coalesced stage of C into LDS
        const float4* cg = (const float4*)Cin;
        float4* cs = (float4*)Cs;
        #pragma unroll
        for (int j = 0; j < 16; ++j)
            cs[threadIdx.x + j * 256] = cg[threadIdx.x + j * 256];
    }
    __syncthreads();

    float p0[DIM], p1[DIM];
    {
        const float4* r0 = (const float4*)(data + (size_t)i0 * DIM);
        const float4* r1 = (const float4*)(data + (size_t)i1 * DIM);
        #pragma unroll
        for (int j = 0; j < 16; ++j) {
            float4 v0 = r0[j], v1 = r1[j];
            p0[4 * j + 0] = v0.x; p0[4 * j + 1] = v0.y;
            p0[4 * j + 2] = v0.z; p0[4 * j + 3] = v0.w;
            p1[4 * j + 0] = v1.x; p1[4 * j + 1] = v1.y;
            p1[4 * j + 2] = v1.z; p1[4 * j + 3] = v1.w;
        }
    }
    float xx0 = seq_rowsum_sq64(p0);
    float xx1 = seq_rowsum_sq64(p1);

    float bd0 = INFINITY, bd1 = INFINITY;
    int bk0 = 0, bk1 = 0;
    for (int k0 = 0; k0 < KC; k0 += 4) {
        const float4* c0 = (const float4*)(Cs + (size_t)k0 * DIM);   // 16 b128/k
        float a00 = 0.f, a01 = 0.f, a02 = 0.f, a03 = 0.f;
        float a10 = 0.f, a11 = 0.f, a12 = 0.f, a13 = 0.f;
        #pragma unroll
        for (int dq = 0; dq < 16; ++dq) {
            float4 c_0 = c0[dq];
            float4 c_1 = c0[16 + dq];
            float4 c_2 = c0[32 + dq];
            float4 c_3 = c0[48 + dq];
            int d = dq * 4;
            // k chains: ascending d (x,y,z,w) — strict order per chain
            a00 = fmaf(c_0.x, p0[d + 0], a00); a00 = fmaf(c_0.y, p0[d + 1], a00);
            a00 = fmaf(c_0.z, p0[d + 2], a00); a00 = fmaf(c_0.w, p0[d + 3], a00);
            a01 = fmaf(c_1.x, p0[d + 0], a01); a01 = fmaf(c_1.y, p0[d + 1], a01);
            a01 = fmaf(c_1.z, p0[d + 2], a01); a01 = fmaf(c_1.w, p0[d + 3], a01);
            a02 = fmaf(c_2.x, p0[d + 0], a02); a02 = fmaf(c_2.y, p0[d + 1], a02);
            a02 = fmaf(c_2.z, p0[d + 2], a02); a02 = fmaf(c_2.w, p0[d + 3], a02);
            a03 = fmaf(c_3.x, p0[d + 0], a03); a03 = fmaf(c_3.y, p0[d + 1], a03);
            a03 = fmaf(c_3.z, p0[d + 2], a03); a03 = fmaf(c_3.w, p0[d + 3], a03);
            a10 = fmaf(c_0.x, p1[d + 0], a10); a10 = fmaf(c_0.y, p1[d + 1], a10);
            a10 = fmaf(c_0.z, p1[d + 2], a10); a10 = fmaf(c_0.w, p1[d + 3], a10);
            a11 = fmaf(c_1.x, p1[d + 0], a11); a11 = fmaf(c_1.y, p1[d + 1], a11);
            a11 = fmaf(c_1.z, p1[d + 2], a11); a11 = fmaf(c_1.w, p1[d + 3], a11);
            a12 = fmaf(c_2.x, p1[d + 0], a12); a12 = fmaf(c_2.y, p1[d + 1], a12);
            a12 = fmaf(c_2.z, p1[d + 2], a12); a12 = fmaf(c_2.w, p1[d + 3], a12);
            a13 = fmaf(c_3.x, p1[d + 0], a13); a13 = fmaf(c_3.y, p1[d + 1], a13);
            a13 = fmaf(c_3.z, p1[d + 2], a13); a13 = fmaf(c_3.w, p1[d + 3], a13);
        }
        float c2_0 = c2[k0 + 0], c2_1 = c2[k0 + 1];
        float c2_2 = c2[k0 + 2], c2_3 = c2[k0 + 3];
        float e00 = (xx0 + c2_0) - 2.f * a00;
        float e01 = (xx0 + c2_1) - 2.f * a01;
        float e02 = (xx0 + c2_2) - 2.f * a02;
        float e03 = (xx0 + c2_3) - 2.f * a03;
        float e10 = (xx1 + c2_0) - 2.f * a10;
        float e11 = (xx1 + c2_1) - 2.f * a11;
        float e12 = (xx1 + c2_2) - 2.f * a12;
        float e13 = (xx1 + c2_3) - 2.f * a13;
        if (e00 < bd0) { bd0 = e00; bk0 = k0 + 0; }
        if (e01 < bd0) { bd0 = e01; bk0 = k0 + 1; }
        if (e02 < bd0) { bd0 = e02; bk0 = k0 + 2; }
        if (e03 < bd0) { bd0 = e03; bk0 = k0 + 3; }
        if (e10 < bd1) { bd1 = e10; bk1 = k0 + 0; }
        if (e11 < bd1) { bd1 = e11; bk1 = k0 + 1; }
        if (e12 < bd1) { bd1 = e12; bk1 = k0 + 2; }
        if (e13 < bd1) { bd1 = e13; bk1 = k0 + 3; }
    }
    labels[i0] = bk0;
    labels[i1] = bk1;
}

// ---- sort pass A: per-chunk histogram
__global__ __launch_bounds__(256) void hist_k(
    const int* __restrict__ labels, int* __restrict__ hist,
    const int* __restrict__ done)
{
    if (*done) return;
    __shared__ int h[KC];
    int b = blockIdx.x;
    h[threadIdx.x] = 0;
    __syncthreads();
    int base = b * 1024;
    for (int j = threadIdx.x; j < 1024; j += 256)
        atomicAdd(&h[labels[base + j]], 1);
    __syncthreads();
    hist[b * KC + threadIdx.x] = h[threadIdx.x];
}

// ---- sort pass B: column prefix + exclusive scan (integer, order-free)
__global__ __launch_bounds__(256) void prefix_k(
    int* __restrict__ hist, int* __restrict__ seg_start,
    float* __restrict__ counts, const int* __restrict__ done)
{
    if (*done) return;
    int k = threadIdx.x;
    int run = 0;
    #pragma unroll 8
    for (int b = 0; b < 256; ++b) {
        int v = hist[b * KC + k];
        hist[b * KC + k] = run;
        run += v;
    }
    __shared__ int sc[KC];
    sc[k] = run;
    __syncthreads();
    for (int off = 1; off < KC; off <<= 1) {
        int v = (k >= off) ? sc[k - off] : 0;
        __syncthreads();
        sc[k] += v;
        __syncthreads();
    }
    int base = sc[k] - run;
    seg_start[k] = base;
    if (k == 0) seg_start[KC] = N_PTS;
    counts[k] = (float)run;
    #pragma unroll 8
    for (int b = 0; b < 256; ++b)
        hist[b * KC + k] += base;
}

// ---- sort pass C: order-preserving scatter (ascending j per chunk)
__global__ __launch_bounds__(256) void scatter_k(
    const int* __restrict__ labels, const int* __restrict__ hist,
    int* __restrict__ order, const int* __restrict__ done)
{
    if (*done) return;
    __shared__ int lab_s[1024];
    int b = blockIdx.x, k = threadIdx.x;
    int base = b * 1024;
    for (int j = k; j < 1024; j += 256) lab_s[j] = labels[base + j];
    __syncthreads();
    int pos = hist[b * KC + k];
    for (int j = 0; j < 1024; ++j) {
        if (lab_s[j] == k) order[pos++] = base + j;
    }
}

// ---- segment sum, transposed+swizzled LDS pipeline (R24 validated).
__global__ __launch_bounds__(512, 1) void sum_pipe4(
    const float* __restrict__ data, const int* __restrict__ order,
    const int* __restrict__ seg_start, float* __restrict__ sums,
    const int* __restrict__ done)
{
    if (*done) return;
    __shared__ float buf[2][DIM][CHUNK];    // 128 KB
    int k = blockIdx.x;
    int t = threadIdx.x;
    int beg = seg_start[k], end = seg_start[k + 1];
    int n = end - beg;
    int nchunk = (n + CHUNK - 1) / CHUNK;
    bool stager = (t >= 64);
    int st = t - 64;                        // 0..447

    int gg[3], qq[3];
    #pragma unroll
    for (int i = 0; i < 3; ++i) {
        int G = st + i * 448;
        gg[i] = G >> 4;
        qq[i] = G & 15;
    }
    int ordA[12];
    const float4* d4 = (const float4*)data;

#define ORDX(cc)                                                              \
    {                                                                         \
        int _b = beg + (cc) * CHUNK;                                          \
        int _m = n - (cc) * CHUNK; if (_m > CHUNK) _m = CHUNK;                \
        _Pragma("unroll")                                                     \
        for (int i = 0; i < 3; ++i) {                                         \
            _Pragma("unroll")                                                 \
            for (int r = 0; r < 4; ++r) {                                     \
                int _rr = 4 * gg[i] + r; if (_rr >= _m) _rr = _m - 1;         \
                ordA[i * 4 + r] = order[_b + _rr];                            \
            }                                                                 \
        }                                                                     \
    }
#define STAGEX(cc, which)                                                     \
    {                                                                         \
        int _m = n - (cc) * CHUNK; if (_m > CHUNK) _m = CHUNK;                \
        int _ng = (_m + 3) >> 2;                                              \
        float4* _bp = (float4*)&buf[which][0][0];                             \
        _Pragma("unroll")                                                     \
        for (int i = 0; i < 3; ++i) {                                         \
            if (gg[i] < _ng) {                                                \
                float4 a0 = d4[(size_t)ordA[i * 4 + 0] * 16 + qq[i]];         \
                float4 a1 = d4[(size_t)ordA[i * 4 + 1] * 16 + qq[i]];         \
                float4 a2 = d4[(size_t)ordA[i * 4 + 2] * 16 + qq[i]];         \
                float4 a3 = d4[(size_t)ordA[i * 4 + 3] * 16 + qq[i]];         \
                int _d0 = qq[i] * 4;                                          \
                _bp[(_d0 + 0) * (CHUNK / 4) + (gg[i] ^ ((_d0 + 0) & 7))] =    \
                    make_float4(a0.x, a1.x, a2.x, a3.x);                      \
                _bp[(_d0 + 1) * (CHUNK / 4) + (gg[i] ^ ((_d0 + 1) & 7))] =    \
                    make_float4(a0.y, a1.y, a2.y, a3.y);                      \
                _bp[(_d0 + 2) * (CHUNK / 4) + (gg[i] ^ ((_d0 + 2) & 7))] =    \
                    make_float4(a0.z, a1.z, a2.z, a3.z);                      \
                _bp[(_d0 + 3) * (CHUNK / 4) + (gg[i] ^ ((_d0 + 3) & 7))] =    \
                    make_float4(a0.w, a1.w, a2.w, a3.w);                      \
            }                                                                 \
        }                                                                     \
    }

    if (stager && nchunk > 0) {
        ORDX(0);
        STAGEX(0, 0);
        if (nchunk > 1) ORDX(1);
    }
    __syncthreads();

    float s = 0.f;
    int x7 = t & 7;
    for (int c = 0; c < nchunk; ++c) {
        if (stager) {
            if (c + 1 < nchunk) STAGEX(c + 1, (c + 1) & 1);
            if (c + 2 < nchunk) ORDX(c + 2);
        } else {
            int m = n - c * CHUNK; if (m > CHUNK) m = CHUNK;
            int mg = m >> 2;
            int cur = c & 1;
            const float4* rp = (const float4*)&buf[cur][t][0];
            #pragma unroll 8
            for (int g = 0; g < mg; ++g) {
                float4 v = rp[g ^ x7];
                s = s + v.x; s = s + v.y; s = s + v.z; s = s + v.w;
            }
            for (int j = mg * 4; j < m; ++j)
                s = s + buf[cur][t][(((j >> 2) ^ x7) << 2) + (j & 3)];
        }
        __syncthreads();
    }
#undef ORDX
#undef STAGEX
    if (t < 64) sums[k * DIM + t] = s;
}

// fallback segment-sum (validated R11) when ws has no room for sort buffers
__global__ __launch_bounds__(64) void accum_scan(
    const float* __restrict__ data, const int* __restrict__ labels,
    float* __restrict__ sums, float* __restrict__ counts,
    const int* __restrict__ done)
{
    if (*done) return;
    int k = blockIdx.x;
    int d = threadIdx.x;
    __shared__ int lab_s[1024];
    float s = 0.f;
    int cnt = 0;
    for (int base = 0; base < N_PTS; base += 1024) {
        for (int j = d; j < 1024; j += 64) lab_s[j] = labels[base + j];
        __syncthreads();
        #pragma unroll 8
        for (int j = 0; j < 1024; ++j) {
            if (lab_s[j] == k) { s = s + data[(size_t)(base + j) * DIM + d]; ++cnt; }
        }
        __syncthreads();
    }
    sums[k * DIM + d] = s;
    if (d == 0) counts[k] = (float)cnt;
}

// ---- update + c2 fused (validated)
__global__ __launch_bounds__(256) void update_c2_k(
    float* __restrict__ C, const float* __restrict__ sums,
    const float* __restrict__ counts, float* __restrict__ c2,
    int* __restrict__ nanidx, int* __restrict__ done)
{
    if (*done) return;
    __shared__ double red[256];
    int k = threadIdx.x;

    float cnt = counts[k];
    float nc[DIM];
    double local = 0.0;
    #pragma unroll
    for (int d = 0; d < DIM; ++d) {
        float v = sums[k * DIM + d] / cnt;
        nc[d] = v;
        float old = C[k * DIM + d];
        double diff = (double)v - (double)old;
        local = fma(diff, diff, local);
        C[k * DIM + d] = v;
    }
    c2[k] = seq_rowsum_sq64(nc);

    red[k] = local;
    __syncthreads();
    if (k == 0) {
        int ni = -1;
        for (int kk = 0; kk < KC; ++kk)
            if (isnan(c2[kk])) { ni = kk; break; }
        *nanidx = ni;
    }
    for (int s = 128; s > 0; s >>= 1) {
        if (k < s) red[k] += red[k + s];
        __syncthreads();
    }
    if (k == 0 && red[0] < 1e-8) *done = 1;    // (1e-4)^2, NaN stays not-done
}

extern "C" void kernel_launch(void* const* d_in, const int* in_sizes, int n_in,
                              void* d_out, int out_size, void* d_ws, size_t ws_size,
                              hipStream_t stream)
{
    const float* data = (const float*)d_in[0];
    const void*  idx  = d_in[1];
    int* labels = (int*)d_out;

    float* C      = (float*)d_ws;               // 16384 f
    float* sums   = C + KC * DIM;               // 16384 f
    float* counts = sums + KC * DIM;            // 256 f
    float* c2     = counts + KC;                // 256 f
    int*   done      = (int*)(c2 + KC);
    int*   mode      = done + 1;
    int*   nanidx    = done + 2;
    int*   seg_start = done + 4;                // 257 ints
    int*   hist      = seg_start + 260;         // 65536 ints
    int*   order     = hist + KC * 256;         // 262144 ints
    size_t need_sort = (size_t)((char*)(order + N_PTS) - (char*)d_ws);
    bool fast = ws_size >= need_sort;           // ~1.4 MB

    detect_idx<<<1, 1, 0, stream>>>((const int*)idx, mode);
    init_gather<<<64, 256, 0, stream>>>(data, idx, mode, C, done);
    c2_init<<<1, 256, 0, stream>>>(C, c2, nanidx);

    for (int it = 0; it < MAX_ITERS; ++it) {
        assign_k<<<N_PTS / 512, 256, 0, stream>>>(data, C, c2, nanidx, labels, done);
        if (fast) {
            hist_k<<<256, 256, 0, stream>>>(labels, hist, done);
            prefix_k<<<1, 256, 0, stream>>>(hist, seg_start, counts, done);
            scatter_k<<<256, 256, 0, stream>>>(labels, hist, order, done);
            sum_pipe4<<<KC, 512, 0, stream>>>(data, order, seg_start, sums, done);
        } else {
            accum_scan<<<KC, 64, 0, stream>>>(data, labels, sums, counts, done);
        }
        update_c2_k<<<1, 256, 0, stream>>>(C, sums, counts, c2, nanidx, done);
    }
}

// Round 29
// 2551.415 us; speedup vs baseline: 2.4360x; 1.0530x over previous
//
#include <hip/hip_runtime.h>
#include <math.h>

#define N_PTS 262144
#define KC 256
#define DIM 64
#define MAX_ITERS 10
#define CHUNK 256

// ===========================================================================
// Bit-exact XLA:CPU f32 arithmetic (validated R11-R28 — DO NOT ALTER):
//   x2/c2: rounded squares (fmaf(v,v,0)) + strict sequential f32 add chain
//   dot:   ascending-k FMA chain;  d2 = (x2 + c2) - 2*dot
//   argmin: strict-< first-min, first-NaN override
//   segment_sum: per (k,d), i-ascending sequential plain f32 adds
//   update: f32 sums/counts division (0/0 -> NaN)
// R29: skip dead work — final iteration's sort+sum+update compute C10 which
// is never read (labels = argmin vs C9). Saves ~180us/call. Assign (R28:
// LDS-staged C, M_TILE=2) and sum (R24: transposed+swizzled LDS pipeline)
// unchanged.
// ===========================================================================

__device__ __forceinline__ float seq_rowsum_sq64(const float* p)
{
    float s = fmaf(p[0], p[0], 0.f);
    #pragma unroll
    for (int d = 1; d < DIM; ++d) s = s + fmaf(p[d], p[d], 0.f);
    return s;
}

__global__ void detect_idx(const int* __restrict__ a, int* __restrict__ mode)
{
    int zeros = 0;
    for (int j = 1; j < 256; j += 2) zeros += (a[j] == 0);
    *mode = (zeros >= 2) ? 1 : 0;
}

__global__ __launch_bounds__(256) void init_gather(
    const float* __restrict__ data, const void* __restrict__ idxraw,
    const int* __restrict__ mode,
    float* __restrict__ C, int* __restrict__ done)
{
    int t = blockIdx.x * 256 + threadIdx.x;
    if (t < KC * DIM) {
        int k = t >> 6;
        long long src = (*mode) ? ((const long long*)idxraw)[k]
                                : (long long)((const int*)idxraw)[k];
        C[t] = data[(size_t)src * DIM + (t & 63)];
    }
    if (t == 0) *done = 0;
}

__global__ __launch_bounds__(256) void c2_init(
    const float* __restrict__ C, float* __restrict__ c2, int* __restrict__ nanidx)
{
    int k = threadIdx.x;
    float p[DIM];
    #pragma unroll
    for (int d = 0; d < DIM; ++d) p[d] = C[k * DIM + d];
    c2[k] = seq_rowsum_sq64(p);
    __syncthreads();
    if (k == 0) {
        int ni = -1;
        for (int kk = 0; kk < KC; ++kk)
            if (isnan(c2[kk])) { ni = kk; break; }
        *nanidx = ni;
    }
}

// assign (R28 validated): LDS-staged C + 2-point register blocking.
__global__ __launch_bounds__(256, 2) void assign_k(
    const float* __restrict__ data, const float* __restrict__ Cin,
    const float* __restrict__ c2, const int* __restrict__ nanidx,
    int* __restrict__ labels, const int* __restrict__ done)
{
    if (*done) return;                       // block-uniform
    __shared__ float Cs[KC * DIM];           // 64 KB
    int i0 = blockIdx.x * 256 + threadIdx.x;
    int i1 = i0 + N_PTS / 2;
    int ni = *nanidx;
    if (ni >= 0) { labels[i0] = ni; labels[i1] = ni; return; }   // uniform

    {
        const float4* cg = (const float4*)Cin;
        float4* cs = (float4*)Cs;
        #pragma unroll
        for (int j = 0; j < 16; ++j)
            cs[threadIdx.x + j * 256] = cg[threadIdx.x + j * 256];
    }
    __syncthreads();

    float p0[DIM], p1[DIM];
    {
        const float4* r0 = (const float4*)(data + (size_t)i0 * DIM);
        const float4* r1 = (const float4*)(data + (size_t)i1 * DIM);
        #pragma unroll
        for (int j = 0; j < 16; ++j) {
            float4 v0 = r0[j], v1 = r1[j];
            p0[4 * j + 0] = v0.x; p0[4 * j + 1] = v0.y;
            p0[4 * j + 2] = v0.z; p0[4 * j + 3] = v0.w;
            p1[4 * j + 0] = v1.x; p1[4 * j + 1] = v1.y;
            p1[4 * j + 2] = v1.z; p1[4 * j + 3] = v1.w;
        }
    }
    float xx0 = seq_rowsum_sq64(p0);
    float xx1 = seq_rowsum_sq64(p1);

    float bd0 = INFINITY, bd1 = INFINITY;
    int bk0 = 0, bk1 = 0;
    for (int k0 = 0; k0 < KC; k0 += 4) {
        const float4* c0 = (const float4*)(Cs + (size_t)k0 * DIM);
        float a00 = 0.f, a01 = 0.f, a02 = 0.f, a03 = 0.f;
        float a10 = 0.f, a11 = 0.f, a12 = 0.f, a13 = 0.f;
        #pragma unroll
        for (int dq = 0; dq < 16; ++dq) {
            float4 c_0 = c0[dq];
            float4 c_1 = c0[16 + dq];
            float4 c_2 = c0[32 + dq];
            float4 c_3 = c0[48 + dq];
            int d = dq * 4;
            a00 = fmaf(c_0.x, p0[d + 0], a00); a00 = fmaf(c_0.y, p0[d + 1], a00);
            a00 = fmaf(c_0.z, p0[d + 2], a00); a00 = fmaf(c_0.w, p0[d + 3], a00);
            a01 = fmaf(c_1.x, p0[d + 0], a01); a01 = fmaf(c_1.y, p0[d + 1], a01);
            a01 = fmaf(c_1.z, p0[d + 2], a01); a01 = fmaf(c_1.w, p0[d + 3], a01);
            a02 = fmaf(c_2.x, p0[d + 0], a02); a02 = fmaf(c_2.y, p0[d + 1], a02);
            a02 = fmaf(c_2.z, p0[d + 2], a02); a02 = fmaf(c_2.w, p0[d + 3], a02);
            a03 = fmaf(c_3.x, p0[d + 0], a03); a03 = fmaf(c_3.y, p0[d + 1], a03);
            a03 = fmaf(c_3.z, p0[d + 2], a03); a03 = fmaf(c_3.w, p0[d + 3], a03);
            a10 = fmaf(c_0.x, p1[d + 0], a10); a10 = fmaf(c_0.y, p1[d + 1], a10);
            a10 = fmaf(c_0.z, p1[d + 2], a10); a10 = fmaf(c_0.w, p1[d + 3], a10);
            a11 = fmaf(c_1.x, p1[d + 0], a11); a11 = fmaf(c_1.y, p1[d + 1], a11);
            a11 = fmaf(c_1.z, p1[d + 2], a11); a11 = fmaf(c_1.w, p1[d + 3], a11);
            a12 = fmaf(c_2.x, p1[d + 0], a12); a12 = fmaf(c_2.y, p1[d + 1], a12);
            a12 = fmaf(c_2.z, p1[d + 2], a12); a12 = fmaf(c_2.w, p1[d + 3], a12);
            a13 = fmaf(c_3.x, p1[d + 0], a13); a13 = fmaf(c_3.y, p1[d + 1], a13);
            a13 = fmaf(c_3.z, p1[d + 2], a13); a13 = fmaf(c_3.w, p1[d + 3], a13);
        }
        float c2_0 = c2[k0 + 0], c2_1 = c2[k0 + 1];
        float c2_2 = c2[k0 + 2], c2_3 = c2[k0 + 3];
        float e00 = (xx0 + c2_0) - 2.f * a00;
        float e01 = (xx0 + c2_1) - 2.f * a01;
        float e02 = (xx0 + c2_2) - 2.f * a02;
        float e03 = (xx0 + c2_3) - 2.f * a03;
        float e10 = (xx1 + c2_0) - 2.f * a10;
        float e11 = (xx1 + c2_1) - 2.f * a11;
        float e12 = (xx1 + c2_2) - 2.f * a12;
        float e13 = (xx1 + c2_3) - 2.f * a13;
        if (e00 < bd0) { bd0 = e00; bk0 = k0 + 0; }
        if (e01 < bd0) { bd0 = e01; bk0 = k0 + 1; }
        if (e02 < bd0) { bd0 = e02; bk0 = k0 + 2; }
        if (e03 < bd0) { bd0 = e03; bk0 = k0 + 3; }
        if (e10 < bd1) { bd1 = e10; bk1 = k0 + 0; }
        if (e11 < bd1) { bd1 = e11; bk1 = k0 + 1; }
        if (e12 < bd1) { bd1 = e12; bk1 = k0 + 2; }
        if (e13 < bd1) { bd1 = e13; bk1 = k0 + 3; }
    }
    labels[i0] = bk0;
    labels[i1] = bk1;
}

// ---- sort pass A: per-chunk histogram
__global__ __launch_bounds__(256) void hist_k(
    const int* __restrict__ labels, int* __restrict__ hist,
    const int* __restrict__ done)
{
    if (*done) return;
    __shared__ int h[KC];
    int b = blockIdx.x;
    h[threadIdx.x] = 0;
    __syncthreads();
    int base = b * 1024;
    for (int j = threadIdx.x; j < 1024; j += 256)
        atomicAdd(&h[labels[base + j]], 1);
    __syncthreads();
    hist[b * KC + threadIdx.x] = h[threadIdx.x];
}

// ---- sort pass B: column prefix + exclusive scan (integer, order-free)
__global__ __launch_bounds__(256) void prefix_k(
    int* __restrict__ hist, int* __restrict__ seg_start,
    float* __restrict__ counts, const int* __restrict__ done)
{
    if (*done) return;
    int k = threadIdx.x;
    int run = 0;
    #pragma unroll 8
    for (int b = 0; b < 256; ++b) {
        int v = hist[b * KC + k];
        hist[b * KC + k] = run;
        run += v;
    }
    __shared__ int sc[KC];
    sc[k] = run;
    __syncthreads();
    for (int off = 1; off < KC; off <<= 1) {
        int v = (k >= off) ? sc[k - off] : 0;
        __syncthreads();
        sc[k] += v;
        __syncthreads();
    }
    int base = sc[k] - run;
    seg_start[k] = base;
    if (k == 0) seg_start[KC] = N_PTS;
    counts[k] = (float)run;
    #pragma unroll 8
    for (int b = 0; b < 256; ++b)
        hist[b * KC + k] += base;
}

// ---- sort pass C: order-preserving scatter (ascending j per chunk)
__global__ __launch_bounds__(256) void scatter_k(
    const int* __restrict__ labels, const int* __restrict__ hist,
    int* __restrict__ order, const int* __restrict__ done)
{
    if (*done) return;
    __shared__ int lab_s[1024];
    int b = blockIdx.x, k = threadIdx.x;
    int base = b * 1024;
    for (int j = k; j < 1024; j += 256) lab_s[j] = labels[base + j];
    __syncthreads();
    int pos = hist[b * KC + k];
    for (int j = 0; j < 1024; ++j) {
        if (lab_s[j] == k) order[pos++] = base + j;
    }
}

// ---- segment sum, transposed+swizzled LDS pipeline (R24 validated).
__global__ __launch_bounds__(512, 1) void sum_pipe4(
    const float* __restrict__ data, const int* __restrict__ order,
    const int* __restrict__ seg_start, float* __restrict__ sums,
    const int* __restrict__ done)
{
    if (*done) return;
    __shared__ float buf[2][DIM][CHUNK];    // 128 KB
    int k = blockIdx.x;
    int t = threadIdx.x;
    int beg = seg_start[k], end = seg_start[k + 1];
    int n = end - beg;
    int nchunk = (n + CHUNK - 1) / CHUNK;
    bool stager = (t >= 64);
    int st = t - 64;                        // 0..447

    int gg[3], qq[3];
    #pragma unroll
    for (int i = 0; i < 3; ++i) {
        int G = st + i * 448;
        gg[i] = G >> 4;
        qq[i] = G & 15;
    }
    int ordA[12];
    const float4* d4 = (const float4*)data;

#define ORDX(cc)                                                              \
    {                                                                         \
        int _b = beg + (cc) * CHUNK;                                          \
        int _m = n - (cc) * CHUNK; if (_m > CHUNK) _m = CHUNK;                \
        _Pragma("unroll")                                                     \
        for (int i = 0; i < 3; ++i) {                                         \
            _Pragma("unroll")                                                 \
            for (int r = 0; r < 4; ++r) {                                     \
                int _rr = 4 * gg[i] + r; if (_rr >= _m) _rr = _m - 1;         \
                ordA[i * 4 + r] = order[_b + _rr];                            \
            }                                                                 \
        }                                                                     \
    }
#define STAGEX(cc, which)                                                     \
    {                                                                         \
        int _m = n - (cc) * CHUNK; if (_m > CHUNK) _m = CHUNK;                \
        int _ng = (_m + 3) >> 2;                                              \
        float4* _bp = (float4*)&buf[which][0][0];                             \
        _Pragma("unroll")                                                     \
        for (int i = 0; i < 3; ++i) {                                         \
            if (gg[i] < _ng) {                                                \
                float4 a0 = d4[(size_t)ordA[i * 4 + 0] * 16 + qq[i]];         \
                float4 a1 = d4[(size_t)ordA[i * 4 + 1] * 16 + qq[i]];         \
                float4 a2 = d4[(size_t)ordA[i * 4 + 2] * 16 + qq[i]];         \
                float4 a3 = d4[(size_t)ordA[i * 4 + 3] * 16 + qq[i]];         \
                int _d0 = qq[i] * 4;                                          \
                _bp[(_d0 + 0) * (CHUNK / 4) + (gg[i] ^ ((_d0 + 0) & 7))] =    \
                    make_float4(a0.x, a1.x, a2.x, a3.x);                      \
                _bp[(_d0 + 1) * (CHUNK / 4) + (gg[i] ^ ((_d0 + 1) & 7))] =    \
                    make_float4(a0.y, a1.y, a2.y, a3.y);                      \
                _bp[(_d0 + 2) * (CHUNK / 4) + (gg[i] ^ ((_d0 + 2) & 7))] =    \
                    make_float4(a0.z, a1.z, a2.z, a3.z);                      \
                _bp[(_d0 + 3) * (CHUNK / 4) + (gg[i] ^ ((_d0 + 3) & 7))] =    \
                    make_float4(a0.w, a1.w, a2.w, a3.w);                      \
            }                                                                 \
        }                                                                     \
    }

    if (stager && nchunk > 0) {
        ORDX(0);
        STAGEX(0, 0);
        if (nchunk > 1) ORDX(1);
    }
    __syncthreads();

    float s = 0.f;
    int x7 = t & 7;
    for (int c = 0; c < nchunk; ++c) {
        if (stager) {
            if (c + 1 < nchunk) STAGEX(c + 1, (c + 1) & 1);
            if (c + 2 < nchunk) ORDX(c + 2);
        } else {
            int m = n - c * CHUNK; if (m > CHUNK) m = CHUNK;
            int mg = m >> 2;
            int cur = c & 1;
            const float4* rp = (const float4*)&buf[cur][t][0];
            #pragma unroll 8
            for (int g = 0; g < mg; ++g) {
                float4 v = rp[g ^ x7];
                s = s + v.x; s = s + v.y; s = s + v.z; s = s + v.w;
            }
            for (int j = mg * 4; j < m; ++j)
                s = s + buf[cur][t][(((j >> 2) ^ x7) << 2) + (j & 3)];
        }
        __syncthreads();
    }
#undef ORDX
#undef STAGEX
    if (t < 64) sums[k * DIM + t] = s;
}

// fallback segment-sum (validated R11) when ws has no room for sort buffers
__global__ __launch_bounds__(64) void accum_scan(
    const float* __restrict__ data, const int* __restrict__ labels,
    float* __restrict__ sums, float* __restrict__ counts,
    const int* __restrict__ done)
{
    if (*done) return;
    int k = blockIdx.x;
    int d = threadIdx.x;
    __shared__ int lab_s[1024];
    float s = 0.f;
    int cnt = 0;
    for (int base = 0; base < N_PTS; base += 1024) {
        for (int j = d; j < 1024; j += 64) lab_s[j] = labels[base + j];
        __syncthreads();
        #pragma unroll 8
        for (int j = 0; j < 1024; ++j) {
            if (lab_s[j] == k) { s = s + data[(size_t)(base + j) * DIM + d]; ++cnt; }
        }
        __syncthreads();
    }
    sums[k * DIM + d] = s;
    if (d == 0) counts[k] = (float)cnt;
}

// ---- update + c2 fused (validated)
__global__ __launch_bounds__(256) void update_c2_k(
    float* __restrict__ C, const float* __restrict__ sums,
    const float* __restrict__ counts, float* __restrict__ c2,
    int* __restrict__ nanidx, int* __restrict__ done)
{
    if (*done) return;
    __shared__ double red[256];
    int k = threadIdx.x;

    float cnt = counts[k];
    float nc[DIM];
    double local = 0.0;
    #pragma unroll
    for (int d = 0; d < DIM; ++d) {
        float v = sums[k * DIM + d] / cnt;
        nc[d] = v;
        float old = C[k * DIM + d];
        double diff = (double)v - (double)old;
        local = fma(diff, diff, local);
        C[k * DIM + d] = v;
    }
    c2[k] = seq_rowsum_sq64(nc);

    red[k] = local;
    __syncthreads();
    if (k == 0) {
        int ni = -1;
        for (int kk = 0; kk < KC; ++kk)
            if (isnan(c2[kk])) { ni = kk; break; }
        *nanidx = ni;
    }
    for (int s = 128; s > 0; s >>= 1) {
        if (k < s) red[k] += red[k + s];
        __syncthreads();
    }
    if (k == 0 && red[0] < 1e-8) *done = 1;    // (1e-4)^2, NaN stays not-done
}

extern "C" void kernel_launch(void* const* d_in, const int* in_sizes, int n_in,
                              void* d_out, int out_size, void* d_ws, size_t ws_size,
                              hipStream_t stream)
{
    const float* data = (const float*)d_in[0];
    const void*  idx  = d_in[1];
    int* labels = (int*)d_out;

    float* C      = (float*)d_ws;               // 16384 f
    float* sums   = C + KC * DIM;               // 16384 f
    float* counts = sums + KC * DIM;            // 256 f
    float* c2     = counts + KC;                // 256 f
    int*   done      = (int*)(c2 + KC);
    int*   mode      = done + 1;
    int*   nanidx    = done + 2;
    int*   seg_start = done + 4;                // 257 ints
    int*   hist      = seg_start + 260;         // 65536 ints
    int*   order     = hist + KC * 256;         // 262144 ints
    size_t need_sort = (size_t)((char*)(order + N_PTS) - (char*)d_ws);
    bool fast = ws_size >= need_sort;           // ~1.4 MB

    detect_idx<<<1, 1, 0, stream>>>((const int*)idx, mode);
    init_gather<<<64, 256, 0, stream>>>(data, idx, mode, C, done);
    c2_init<<<1, 256, 0, stream>>>(C, c2, nanidx);

    for (int it = 0; it < MAX_ITERS; ++it) {
        assign_k<<<N_PTS / 512, 256, 0, stream>>>(data, C, c2, nanidx, labels, done);
        if (it == MAX_ITERS - 1) break;     // C10/c2/done are dead after the
                                            // final assign — skip sort+sum+update
        if (fast) {
            hist_k<<<256, 256, 0, stream>>>(labels, hist, done);
            prefix_k<<<1, 256, 0, stream>>>(hist, seg_start, counts, done);
            scatter_k<<<256, 256, 0, stream>>>(labels, hist, order, done);
            sum_pipe4<<<KC, 512, 0, stream>>>(data, order, seg_start, sums, done);
        } else {
            accum_scan<<<KC, 64, 0, stream>>>(data, labels, sums, counts, done);
        }
        update_c2_k<<<1, 256, 0, stream>>>(C, sums, counts, c2, nanidx, done);
    }
}